// Round 2
// baseline (179.874 us; speedup 1.0000x reference)
//
#include <hip/hip_runtime.h>
#include <hip/hip_bf16.h>
#include <math.h>

// N=1e6 points, M=1e5 segments, D=64, K=32. pt_inv is SORTED.
// Strategy: streaming segmented max-scan (wave = 128 contiguous points,
// lane = feature col), monotone-encoded u32 atomicMax for boundary runs,
// plain stores for interior runs, then a small fused GEMM.

#define D_IN 64
#define K_OUT 32
#define RPW 128            // rows (points) per wave in scan kernel
#define WPB 4              // waves per block
#define ENC_NEG_INF 0x007FFFFFu

__device__ __forceinline__ unsigned enc_f32(float f) {
    unsigned u = __float_as_uint(f);
    return (u & 0x80000000u) ? ~u : (u | 0x80000000u);
}
__device__ __forceinline__ float dec_f32(unsigned u) {
    unsigned b = (u & 0x80000000u) ? (u ^ 0x80000000u) : ~u;
    return __uint_as_float(b);
}

__global__ __launch_bounds__(256) void init_pooled_kernel(uint4* __restrict__ p, int n4)
{
    const uint4 v = make_uint4(ENC_NEG_INF, ENC_NEG_INF, ENC_NEG_INF, ENC_NEG_INF);
    for (int i = blockIdx.x * blockDim.x + threadIdx.x; i < n4; i += gridDim.x * blockDim.x)
        p[i] = v;
}

// Streaming segmented max: each wave owns rows [base, base+RPW).
__global__ __launch_bounds__(64 * WPB) void scan_max_kernel(
    const int*   __restrict__ shuffled_ind,
    const float* __restrict__ g,       // [N,64]
    const float* __restrict__ l,       // [N,64]
    const int*   __restrict__ pt_inv,  // [N] sorted
    unsigned*    __restrict__ pooled,  // [M,64] encoded
    int n)
{
    __shared__ int ind_lds[WPB][RPW];
    __shared__ int seg_lds[WPB][RPW];

    const int tid  = threadIdx.x;
    const int wid  = tid >> 6;
    const int lane = tid & 63;
    const int base = (blockIdx.x * WPB + wid) * RPW;
    const int rows = min(RPW, n - base);   // wave-uniform

    #pragma unroll
    for (int j0 = 0; j0 < RPW; j0 += 64) {
        const int r = j0 + lane;
        if (r < rows) {
            ind_lds[wid][r] = shuffled_ind[base + r];
            seg_lds[wid][r] = pt_inv[base + r];
        }
    }
    __syncthreads();
    if (rows <= 0) return;

    int   curSeg   = seg_lds[wid][0];
    int   segFirst = 0;       // chunk-local row where current run started
    float m        = -INFINITY;

    for (int i0 = 0; i0 < rows; i0 += 8) {
        float x[8];
        #pragma unroll
        for (int k = 0; k < 8; ++k) {
            const int i  = min(i0 + k, rows - 1);       // clamped: loads stay in bounds
            const int ind = ind_lds[wid][i];
            x[k] = g[(size_t)ind * D_IN + lane] + l[(size_t)(base + i) * D_IN + lane];
        }
        #pragma unroll
        for (int k = 0; k < 8; ++k) {
            const int i = i0 + k;
            if (i < rows) {                              // wave-uniform branch
                const int seg = seg_lds[wid][i];
                if (seg != curSeg) {
                    // flush run [segFirst, i-1]; interior => single writer => store
                    unsigned* p = pooled + (size_t)curSeg * D_IN + lane;
                    const unsigned e = enc_f32(m);
                    if (segFirst == 0) atomicMax(p, e); else *p = e;
                    curSeg = seg; segFirst = i; m = x[k];
                } else {
                    m = fmaxf(m, x[k]);
                }
            }
        }
    }
    // final run may extend into the next chunk -> atomic
    atomicMax(pooled + (size_t)curSeg * D_IN + lane, enc_f32(m));
}

// Fused decode + (pooled @ W + b) -> relu. One wave per segment.
__global__ __launch_bounds__(256) void gemm_kernel(
    const unsigned* __restrict__ pooled, // [M,64] encoded
    const float*    __restrict__ W,      // [64,32]
    const float*    __restrict__ b,      // [32]
    float*          __restrict__ out,    // [M,32]
    int M)
{
    __shared__ float Ws[D_IN * K_OUT];
    __shared__ float bs[K_OUT];
    __shared__ float pool[WPB][D_IN];

    const int tid = threadIdx.x;
    for (int i = tid; i < D_IN * K_OUT; i += 64 * WPB) Ws[i] = W[i];
    if (tid < K_OUT) bs[tid] = b[tid];

    const int wid  = tid >> 6;
    const int lane = tid & 63;
    const int s    = blockIdx.x * WPB + wid;
    const bool active = (s < M);

    if (active) {
        const unsigned u = pooled[(size_t)s * D_IN + lane];
        pool[wid][lane] = (u == ENC_NEG_INF) ? 0.0f : dec_f32(u);  // empty seg -> 0
    }
    __syncthreads();

    if (active && lane < K_OUT) {
        float acc = bs[lane];
        #pragma unroll
        for (int c = 0; c < D_IN; ++c)
            acc = fmaf(pool[wid][c], Ws[c * K_OUT + lane], acc);
        out[(size_t)s * K_OUT + lane] = fmaxf(acc, 0.0f);
    }
}

// ---------- Fallback path (if ws too small): round-1 design ----------
__global__ __launch_bounds__(256) void seg_starts_kernel(
    const int* __restrict__ pt_inv, int n, int* __restrict__ starts, int M)
{
    int s = blockIdx.x * blockDim.x + threadIdx.x;
    if (s > M) return;
    int lo = 0, hi = n;
    while (lo < hi) { int mid = (lo + hi) >> 1; if (pt_inv[mid] < s) lo = mid + 1; else hi = mid; }
    starts[s] = lo;
}

__global__ __launch_bounds__(256) void pool_gemm_kernel(
    const int* __restrict__ shuffled_ind, const float* __restrict__ g,
    const float* __restrict__ l, const int* __restrict__ starts,
    const float* __restrict__ W, const float* __restrict__ b,
    float* __restrict__ out, int M)
{
    __shared__ float Ws[D_IN * K_OUT];
    __shared__ float bs[K_OUT];
    __shared__ float pool[WPB][D_IN];
    const int tid = threadIdx.x;
    for (int i = tid; i < D_IN * K_OUT; i += 64 * WPB) Ws[i] = W[i];
    if (tid < K_OUT) bs[tid] = b[tid];
    const int wid = tid >> 6, lane = tid & 63;
    const int s = blockIdx.x * WPB + wid;
    const bool active = (s < M);
    float m = -INFINITY;
    if (active) {
        const int p0 = starts[s], p1 = starts[s + 1];
        for (int p = p0; p < p1; ++p) {
            const int ind = shuffled_ind[p];
            m = fmaxf(m, g[(size_t)ind * D_IN + lane] + l[(size_t)p * D_IN + lane]);
        }
        if (p1 <= p0) m = 0.0f;
    }
    if (active) pool[wid][lane] = m;
    __syncthreads();
    if (active && lane < K_OUT) {
        float acc = bs[lane];
        #pragma unroll
        for (int c = 0; c < D_IN; ++c) acc = fmaf(pool[wid][c], Ws[c * K_OUT + lane], acc);
        out[(size_t)s * K_OUT + lane] = fmaxf(acc, 0.0f);
    }
}

extern "C" void kernel_launch(void* const* d_in, const int* in_sizes, int n_in,
                              void* d_out, int out_size, void* d_ws, size_t ws_size,
                              hipStream_t stream)
{
    const int*   shuffled_ind = (const int*)  d_in[0];
    const float* g            = (const float*)d_in[1];
    const float* l            = (const float*)d_in[2];
    const int*   pt_inv       = (const int*)  d_in[3];
    const float* W            = (const float*)d_in[4];
    const float* b            = (const float*)d_in[5];
    float*       out          = (float*)d_out;

    const int N = in_sizes[0];
    const int M = out_size / K_OUT;

    const size_t pooled_bytes = (size_t)M * D_IN * sizeof(unsigned);

    if (ws_size >= pooled_bytes) {
        unsigned* pooled = (unsigned*)d_ws;
        {
            const int n4 = (int)(pooled_bytes / 16);
            init_pooled_kernel<<<512, 256, 0, stream>>>((uint4*)pooled, n4);
        }
        {
            const int rows_per_block = WPB * RPW;
            const int blocks = (N + rows_per_block - 1) / rows_per_block;
            scan_max_kernel<<<blocks, 64 * WPB, 0, stream>>>(
                shuffled_ind, g, l, pt_inv, pooled, N);
        }
        {
            const int blocks = (M + WPB - 1) / WPB;
            gemm_kernel<<<blocks, 64 * WPB, 0, stream>>>(pooled, W, b, out, M);
        }
    } else {
        int* starts = (int*)d_ws;
        {
            const int blocks = (M + 1 + 255) / 256;
            seg_starts_kernel<<<blocks, 256, 0, stream>>>(pt_inv, N, starts, M);
        }
        {
            const int blocks = (M + WPB - 1) / WPB;
            pool_gemm_kernel<<<blocks, 64 * WPB, 0, stream>>>(
                shuffled_ind, g, l, starts, W, b, out, M);
        }
    }
}

// Round 3
// 160.267 us; speedup vs baseline: 1.1223x; 1.1223x over previous
//
#include <hip/hip_runtime.h>
#include <hip/hip_bf16.h>
#include <math.h>

// N=1e6 points, M=1e5 segments, D=64, K=32. pt_inv is SORTED.
// Scan kernel: wave = 128 contiguous points processed in 4-row groups,
// lane = (row-in-group, 16-col-group), float4 loads (1KB/instr),
// per-lane running max with flush-time cross-row reduce,
// monotone-encoded u32 atomicMax only at chunk-boundary runs.

#define D_IN 64
#define K_OUT 32
#define RPW 128            // rows per wave
#define WPB 4              // waves per block
#define ENC_NEG_INF 0x007FFFFFu

__device__ __forceinline__ unsigned enc_f32(float f) {
    unsigned u = __float_as_uint(f);
    return (u & 0x80000000u) ? ~u : (u | 0x80000000u);
}
__device__ __forceinline__ float dec_f32(unsigned u) {
    unsigned b = (u & 0x80000000u) ? (u ^ 0x80000000u) : ~u;
    return __uint_as_float(b);
}

__global__ __launch_bounds__(256) void init_pooled_kernel(uint4* __restrict__ p, int n4)
{
    const uint4 v = make_uint4(ENC_NEG_INF, ENC_NEG_INF, ENC_NEG_INF, ENC_NEG_INF);
    for (int i = blockIdx.x * blockDim.x + threadIdx.x; i < n4; i += gridDim.x * blockDim.x)
        p[i] = v;
}

__global__ __launch_bounds__(64 * WPB) void scan_max_kernel(
    const int*   __restrict__ shuffled_ind,
    const float* __restrict__ g,       // [N,64]
    const float* __restrict__ l,       // [N,64]
    const int*   __restrict__ pt_inv,  // [N] sorted
    unsigned*    __restrict__ pooled,  // [M,64] encoded
    int n)
{
    __shared__ int ind_lds[WPB][RPW];
    __shared__ int seg_lds[WPB][RPW];

    const int tid  = threadIdx.x;
    const int wid  = tid >> 6;
    const int lane = tid & 63;
    const int rp   = lane >> 4;   // row within 4-row group
    const int cg   = lane & 15;   // 16-col group (float4)
    const int base = (blockIdx.x * WPB + wid) * RPW;
    const int rows = min(RPW, n - base);   // wave-uniform

    #pragma unroll
    for (int j0 = 0; j0 < RPW; j0 += 64) {
        const int r = j0 + lane;
        if (r < rows) {
            ind_lds[wid][r] = shuffled_ind[base + r];
            seg_lds[wid][r] = pt_inv[base + r];
        }
    }
    __syncthreads();
    if (rows <= 0) return;

    const int rl      = rows - 1;
    const int ngroups = (rows + 3) >> 2;

    int    curSeg   = seg_lds[wid][0];
    bool   firstRun = true;
    float4 m4 = make_float4(-INFINITY, -INFINITY, -INFINITY, -INFINITY);

    auto load_group = [&](int grp) -> float4 {
        const int irow = min(grp * 4 + rp, rl);          // clamped: always in bounds
        const int ind  = ind_lds[wid][irow];
        const float4 gv = *reinterpret_cast<const float4*>(g + (size_t)ind * D_IN + cg * 4);
        const float4 lv = *reinterpret_cast<const float4*>(l + (size_t)(base + irow) * D_IN + cg * 4);
        return make_float4(gv.x + lv.x, gv.y + lv.y, gv.z + lv.z, gv.w + lv.w);
    };
    auto acc4 = [&](const float4& x) {
        m4.x = fmaxf(m4.x, x.x); m4.y = fmaxf(m4.y, x.y);
        m4.z = fmaxf(m4.z, x.z); m4.w = fmaxf(m4.w, x.w);
    };
    auto do_flush = [&](int seg, bool useAtomic) {
        float4 t = m4;   // reduce the 4 row-replicas (lanes xor 16, xor 32)
        t.x = fmaxf(t.x, __shfl_xor(t.x, 16)); t.y = fmaxf(t.y, __shfl_xor(t.y, 16));
        t.z = fmaxf(t.z, __shfl_xor(t.z, 16)); t.w = fmaxf(t.w, __shfl_xor(t.w, 16));
        t.x = fmaxf(t.x, __shfl_xor(t.x, 32)); t.y = fmaxf(t.y, __shfl_xor(t.y, 32));
        t.z = fmaxf(t.z, __shfl_xor(t.z, 32)); t.w = fmaxf(t.w, __shfl_xor(t.w, 32));
        if (rp == 0) {   // 16 lanes write this segment's 64 floats
            unsigned* p = pooled + (size_t)seg * D_IN + cg * 4;
            const unsigned ex = enc_f32(t.x), ey = enc_f32(t.y),
                           ez = enc_f32(t.z), ew = enc_f32(t.w);
            if (useAtomic) {
                atomicMax(p + 0, ex); atomicMax(p + 1, ey);
                atomicMax(p + 2, ez); atomicMax(p + 3, ew);
            } else {
                *reinterpret_cast<uint4*>(p) = make_uint4(ex, ey, ez, ew);
            }
        }
    };

    // depth-3 software pipeline (named regs only — no runtime-indexed arrays)
    float4 xA = load_group(0);
    float4 xB = load_group(1);
    float4 xC = load_group(2);

    for (int grp = 0; grp < ngroups; ++grp) {
        float4 xD = load_group(grp + 3);   // clamped => safe past the end

        const int i0 = grp * 4;
        const int s3 = seg_lds[wid][min(i0 + 3, rl)];
        if (s3 == curSeg) {
            acc4(xA);                       // whole group in current segment
        } else {
            const int s0 = seg_lds[wid][min(i0 + 0, rl)];
            const int s1 = seg_lds[wid][min(i0 + 1, rl)];
            const int s2 = seg_lds[wid][min(i0 + 2, rl)];
            if (s0 != curSeg) { do_flush(curSeg, firstRun); firstRun = false; curSeg = s0;
                                m4 = make_float4(-INFINITY,-INFINITY,-INFINITY,-INFINITY); }
            if (rp == 0) acc4(xA);
            if (s1 != curSeg) { do_flush(curSeg, firstRun); firstRun = false; curSeg = s1;
                                m4 = make_float4(-INFINITY,-INFINITY,-INFINITY,-INFINITY); }
            if (rp == 1) acc4(xA);
            if (s2 != curSeg) { do_flush(curSeg, firstRun); firstRun = false; curSeg = s2;
                                m4 = make_float4(-INFINITY,-INFINITY,-INFINITY,-INFINITY); }
            if (rp == 2) acc4(xA);
            if (s3 != curSeg) { do_flush(curSeg, firstRun); firstRun = false; curSeg = s3;
                                m4 = make_float4(-INFINITY,-INFINITY,-INFINITY,-INFINITY); }
            if (rp == 3) acc4(xA);
        }
        xA = xB; xB = xC; xC = xD;
    }
    do_flush(curSeg, true);   // final run may span into next chunk
}

// Decode + (pooled @ W + b) -> relu. One wave per 2 segments (all 64 lanes used).
__global__ __launch_bounds__(256) void gemm_kernel(
    const unsigned* __restrict__ pooled, // [M,64] encoded
    const float*    __restrict__ W,      // [64,32]
    const float*    __restrict__ b,      // [32]
    float*          __restrict__ out,    // [M,32]
    int M)
{
    __shared__ float Ws[D_IN * K_OUT];
    __shared__ float bs[K_OUT];
    __shared__ float pool[WPB][2 * D_IN];

    const int tid = threadIdx.x;
    for (int i = tid; i < D_IN * K_OUT; i += 256) Ws[i] = W[i];
    if (tid < K_OUT) bs[tid] = b[tid];

    const int wid  = tid >> 6;
    const int lane = tid & 63;
    const int s0   = (blockIdx.x * WPB + wid) * 2;

    if (s0 < M) {
        const int nvals = min(2, M - s0) * D_IN;   // 64 or 128
        uint2 u = make_uint2(ENC_NEG_INF, ENC_NEG_INF);
        if (lane * 2 < nvals)
            u = *reinterpret_cast<const uint2*>(pooled + (size_t)s0 * D_IN + lane * 2);
        pool[wid][lane * 2 + 0] = (u.x == ENC_NEG_INF) ? 0.0f : dec_f32(u.x);
        pool[wid][lane * 2 + 1] = (u.y == ENC_NEG_INF) ? 0.0f : dec_f32(u.y);
    }
    __syncthreads();

    const int h = lane >> 5;   // which of the 2 segments
    const int k = lane & 31;   // output column
    const int s = s0 + h;
    if (s0 < M && s < M) {
        float acc = bs[k];
        const float* pr = &pool[wid][h * D_IN];
        #pragma unroll
        for (int c = 0; c < D_IN; ++c)
            acc = fmaf(pr[c], Ws[c * K_OUT + k], acc);
        out[(size_t)s * K_OUT + k] = fmaxf(acc, 0.0f);
    }
}

// ---------- Fallback path (if ws too small): round-1 design ----------
__global__ __launch_bounds__(256) void seg_starts_kernel(
    const int* __restrict__ pt_inv, int n, int* __restrict__ starts, int M)
{
    int s = blockIdx.x * blockDim.x + threadIdx.x;
    if (s > M) return;
    int lo = 0, hi = n;
    while (lo < hi) { int mid = (lo + hi) >> 1; if (pt_inv[mid] < s) lo = mid + 1; else hi = mid; }
    starts[s] = lo;
}

__global__ __launch_bounds__(256) void pool_gemm_kernel(
    const int* __restrict__ shuffled_ind, const float* __restrict__ g,
    const float* __restrict__ l, const int* __restrict__ starts,
    const float* __restrict__ W, const float* __restrict__ b,
    float* __restrict__ out, int M)
{
    __shared__ float Ws[D_IN * K_OUT];
    __shared__ float bs[K_OUT];
    __shared__ float pool[WPB][D_IN];
    const int tid = threadIdx.x;
    for (int i = tid; i < D_IN * K_OUT; i += 256) Ws[i] = W[i];
    if (tid < K_OUT) bs[tid] = b[tid];
    const int wid = tid >> 6, lane = tid & 63;
    const int s = blockIdx.x * WPB + wid;
    const bool active = (s < M);
    float m = -INFINITY;
    if (active) {
        const int p0 = starts[s], p1 = starts[s + 1];
        for (int p = p0; p < p1; ++p) {
            const int ind = shuffled_ind[p];
            m = fmaxf(m, g[(size_t)ind * D_IN + lane] + l[(size_t)p * D_IN + lane]);
        }
        if (p1 <= p0) m = 0.0f;
    }
    if (active) pool[wid][lane] = m;
    __syncthreads();
    if (active && lane < K_OUT) {
        float acc = bs[lane];
        #pragma unroll
        for (int c = 0; c < D_IN; ++c) acc = fmaf(pool[wid][c], Ws[c * K_OUT + lane], acc);
        out[(size_t)s * K_OUT + lane] = fmaxf(acc, 0.0f);
    }
}

extern "C" void kernel_launch(void* const* d_in, const int* in_sizes, int n_in,
                              void* d_out, int out_size, void* d_ws, size_t ws_size,
                              hipStream_t stream)
{
    const int*   shuffled_ind = (const int*)  d_in[0];
    const float* g            = (const float*)d_in[1];
    const float* l            = (const float*)d_in[2];
    const int*   pt_inv       = (const int*)  d_in[3];
    const float* W            = (const float*)d_in[4];
    const float* b            = (const float*)d_in[5];
    float*       out          = (float*)d_out;

    const int N = in_sizes[0];
    const int M = out_size / K_OUT;

    const size_t pooled_bytes = (size_t)M * D_IN * sizeof(unsigned);

    if (ws_size >= pooled_bytes) {
        unsigned* pooled = (unsigned*)d_ws;
        {
            const int n4 = (int)(pooled_bytes / 16);
            init_pooled_kernel<<<512, 256, 0, stream>>>((uint4*)pooled, n4);
        }
        {
            const int rows_per_block = WPB * RPW;
            const int blocks = (N + rows_per_block - 1) / rows_per_block;
            scan_max_kernel<<<blocks, 64 * WPB, 0, stream>>>(
                shuffled_ind, g, l, pt_inv, pooled, N);
        }
        {
            const int blocks = (M + 2 * WPB - 1) / (2 * WPB);
            gemm_kernel<<<blocks, 64 * WPB, 0, stream>>>(pooled, W, b, out, M);
        }
    } else {
        int* starts = (int*)d_ws;
        {
            const int blocks = (M + 1 + 255) / 256;
            seg_starts_kernel<<<blocks, 256, 0, stream>>>(pt_inv, N, starts, M);
        }
        {
            const int blocks = (M + WPB - 1) / WPB;
            pool_gemm_kernel<<<blocks, 64 * WPB, 0, stream>>>(
                shuffled_ind, g, l, starts, W, b, out, M);
        }
    }
}

// Round 4
// 152.708 us; speedup vs baseline: 1.1779x; 1.0495x over previous
//
#include <hip/hip_runtime.h>
#include <hip/hip_bf16.h>
#include <math.h>

// N=1e6 points, M=1e5 segments, D=64, K=32. pt_inv is SORTED.
// Strip design: wave = 128 rows as 4 independent 32-row strips (rp = lane>>4).
// Each 16-lane group scans its strip with a per-lane running max over 4 cols
// (cg = lane&15, float4). No LDS, no shuffles, no syncthreads. ind/seg via
// global int4 broadcast loads. Explicit static-index software pipeline:
// data chunk c+1 and meta chunk c+2 in flight at every consume point.
// Interior runs -> plain uint4 store (single writer); strip-boundary runs ->
// u32 monotone-encoded atomicMax.

#define D_IN 64
#define K_OUT 32
#define STRIP 32
#define RPW   128          // 4 strips * 32 rows
#define WPB   4
#define NCHUNK 8           // STRIP / 4
#define ENC_NEG_INF 0x007FFFFFu

__device__ __forceinline__ unsigned enc_f32(float f) {
    unsigned u = __float_as_uint(f);
    return (u & 0x80000000u) ? ~u : (u | 0x80000000u);
}
__device__ __forceinline__ float dec_f32(unsigned u) {
    unsigned b = (u & 0x80000000u) ? (u ^ 0x80000000u) : ~u;
    return __uint_as_float(b);
}

__global__ __launch_bounds__(256) void init_pooled_kernel(uint4* __restrict__ p, int n4)
{
    const uint4 v = make_uint4(ENC_NEG_INF, ENC_NEG_INF, ENC_NEG_INF, ENC_NEG_INF);
    for (int i = blockIdx.x * blockDim.x + threadIdx.x; i < n4; i += gridDim.x * blockDim.x)
        p[i] = v;
}

// Requires n % 4 == 0 (chunks are 16B-aligned and all-or-nothing alive).
__global__ __launch_bounds__(256) void scan_strip_kernel(
    const int*   __restrict__ ind_arr,  // [N] permutation
    const float* __restrict__ g,        // [N,64]
    const float* __restrict__ l,        // [N,64]
    const int*   __restrict__ seg_arr,  // [N] sorted
    unsigned*    __restrict__ pooled,   // [M,64] encoded
    int n)
{
    const int lane  = threadIdx.x & 63;
    const int wave  = (blockIdx.x * blockDim.x + threadIdx.x) >> 6;
    const int rp    = lane >> 4;         // which strip of the wave
    const int cg    = lane & 15;         // 16-col group (float4)
    const int sbase = wave * RPW + rp * STRIP;
    const int nm4   = n - 4;
    const bool aliveStrip = (sbase < n);

    int4   idq[3], sgq[3];               // meta ring (static idx after unroll)
    float4 gx[2][4], lx[2][4];           // data double buffer

#define CROW(c) (min(sbase + 4*(c), nm4))

    // ---- prologue: M(0), M(1) ----
    idq[0] = *(const int4*)(ind_arr + CROW(0));
    sgq[0] = *(const int4*)(seg_arr + CROW(0));
    idq[1] = *(const int4*)(ind_arr + CROW(1));
    sgq[1] = *(const int4*)(seg_arr + CROW(1));

    // ---- D(0) (waits meta0; meta1 stays in flight) ----
    {
        const size_t rb = (size_t)CROW(0);
        gx[0][0] = *(const float4*)(g + (size_t)idq[0].x * D_IN + (cg << 2));
        gx[0][1] = *(const float4*)(g + (size_t)idq[0].y * D_IN + (cg << 2));
        gx[0][2] = *(const float4*)(g + (size_t)idq[0].z * D_IN + (cg << 2));
        gx[0][3] = *(const float4*)(g + (size_t)idq[0].w * D_IN + (cg << 2));
        lx[0][0] = *(const float4*)(l + (rb + 0) * D_IN + (cg << 2));
        lx[0][1] = *(const float4*)(l + (rb + 1) * D_IN + (cg << 2));
        lx[0][2] = *(const float4*)(l + (rb + 2) * D_IN + (cg << 2));
        lx[0][3] = *(const float4*)(l + (rb + 3) * D_IN + (cg << 2));
    }
    // ---- M(2) ----
    idq[2] = *(const int4*)(ind_arr + CROW(2));
    sgq[2] = *(const int4*)(seg_arr + CROW(2));
    // ---- D(1) (waits meta1; D(0), M(2) stay in flight) ----
    {
        const size_t rb = (size_t)CROW(1);
        gx[1][0] = *(const float4*)(g + (size_t)idq[1].x * D_IN + (cg << 2));
        gx[1][1] = *(const float4*)(g + (size_t)idq[1].y * D_IN + (cg << 2));
        gx[1][2] = *(const float4*)(g + (size_t)idq[1].z * D_IN + (cg << 2));
        gx[1][3] = *(const float4*)(g + (size_t)idq[1].w * D_IN + (cg << 2));
        lx[1][0] = *(const float4*)(l + (rb + 0) * D_IN + (cg << 2));
        lx[1][1] = *(const float4*)(l + (rb + 1) * D_IN + (cg << 2));
        lx[1][2] = *(const float4*)(l + (rb + 2) * D_IN + (cg << 2));
        lx[1][3] = *(const float4*)(l + (rb + 3) * D_IN + (cg << 2));
    }

    int    curSeg   = sgq[0].x;
    bool   firstRun = true;
    float4 m4 = make_float4(-INFINITY, -INFINITY, -INFINITY, -INFINITY);

    auto flush_run = [&](bool atomic_) {
        unsigned* p = pooled + (size_t)curSeg * D_IN + (cg << 2);
        const unsigned e0 = enc_f32(m4.x), e1 = enc_f32(m4.y),
                       e2 = enc_f32(m4.z), e3 = enc_f32(m4.w);
        if (atomic_) {
            atomicMax(p + 0, e0); atomicMax(p + 1, e1);
            atomicMax(p + 2, e2); atomicMax(p + 3, e3);
        } else {
            *reinterpret_cast<uint4*>(p) = make_uint4(e0, e1, e2, e3);
        }
    };
    auto prow = [&](int s, const float4& gv, const float4& lv) {
        const float4 x = make_float4(gv.x + lv.x, gv.y + lv.y, gv.z + lv.z, gv.w + lv.w);
        if (s != curSeg) {
            flush_run(firstRun);   // first run of strip may extend backwards -> atomic
            firstRun = false;
            curSeg = s;
            m4 = x;
        } else {
            m4.x = fmaxf(m4.x, x.x); m4.y = fmaxf(m4.y, x.y);
            m4.z = fmaxf(m4.z, x.z); m4.w = fmaxf(m4.w, x.w);
        }
    };

    #pragma unroll
    for (int c = 0; c < NCHUNK; ++c) {
        const int4 sg = sgq[c % 3];
        const bool alive = (sbase + 4 * c < n);   // uniform per 16-lane group
        if (alive) {
            prow(sg.x, gx[c & 1][0], lx[c & 1][0]);
            prow(sg.y, gx[c & 1][1], lx[c & 1][1]);
            prow(sg.z, gx[c & 1][2], lx[c & 1][2]);
            prow(sg.w, gx[c & 1][3], lx[c & 1][3]);
        }
        if (c + 3 < NCHUNK) {                     // M(c+3) -> slot c%3 (now free)
            idq[c % 3] = *(const int4*)(ind_arr + CROW(c + 3));
            sgq[c % 3] = *(const int4*)(seg_arr + CROW(c + 3));
        }
        if (c + 2 < NCHUNK) {                     // D(c+2) -> buf c&1 (now free)
            const int4 id = idq[(c + 2) % 3];
            const size_t rb = (size_t)CROW(c + 2);
            gx[c & 1][0] = *(const float4*)(g + (size_t)id.x * D_IN + (cg << 2));
            gx[c & 1][1] = *(const float4*)(g + (size_t)id.y * D_IN + (cg << 2));
            gx[c & 1][2] = *(const float4*)(g + (size_t)id.z * D_IN + (cg << 2));
            gx[c & 1][3] = *(const float4*)(g + (size_t)id.w * D_IN + (cg << 2));
            lx[c & 1][0] = *(const float4*)(l + (rb + 0) * D_IN + (cg << 2));
            lx[c & 1][1] = *(const float4*)(l + (rb + 1) * D_IN + (cg << 2));
            lx[c & 1][2] = *(const float4*)(l + (rb + 2) * D_IN + (cg << 2));
            lx[c & 1][3] = *(const float4*)(l + (rb + 3) * D_IN + (cg << 2));
        }
    }
    if (aliveStrip) flush_run(true);   // last run may span into the next strip
#undef CROW
}

// Decode + (pooled @ W + b) -> relu. One wave per 2 segments.
__global__ __launch_bounds__(256) void gemm_kernel(
    const unsigned* __restrict__ pooled, // [M,64] encoded
    const float*    __restrict__ W,      // [64,32]
    const float*    __restrict__ b,      // [32]
    float*          __restrict__ out,    // [M,32]
    int M)
{
    __shared__ float Ws[D_IN * K_OUT];
    __shared__ float bs[K_OUT];
    __shared__ float pool[WPB][2 * D_IN];

    const int tid = threadIdx.x;
    for (int i = tid; i < D_IN * K_OUT; i += 256) Ws[i] = W[i];
    if (tid < K_OUT) bs[tid] = b[tid];

    const int wid  = tid >> 6;
    const int lane = tid & 63;
    const int s0   = (blockIdx.x * WPB + wid) * 2;

    if (s0 < M) {
        const int nvals = min(2, M - s0) * D_IN;
        uint2 u = make_uint2(ENC_NEG_INF, ENC_NEG_INF);
        if (lane * 2 < nvals)
            u = *reinterpret_cast<const uint2*>(pooled + (size_t)s0 * D_IN + lane * 2);
        pool[wid][lane * 2 + 0] = (u.x == ENC_NEG_INF) ? 0.0f : dec_f32(u.x);
        pool[wid][lane * 2 + 1] = (u.y == ENC_NEG_INF) ? 0.0f : dec_f32(u.y);
    }
    __syncthreads();

    const int h = lane >> 5;
    const int k = lane & 31;
    const int s = s0 + h;
    if (s0 < M && s < M) {
        float acc = bs[k];
        const float* pr = &pool[wid][h * D_IN];
        #pragma unroll
        for (int c = 0; c < D_IN; ++c)
            acc = fmaf(pr[c], Ws[c * K_OUT + k], acc);
        out[(size_t)s * K_OUT + k] = fmaxf(acc, 0.0f);
    }
}

// ---------- Fallback path (ws too small or n%4!=0): round-1 design ----------
__global__ __launch_bounds__(256) void seg_starts_kernel(
    const int* __restrict__ pt_inv, int n, int* __restrict__ starts, int M)
{
    int s = blockIdx.x * blockDim.x + threadIdx.x;
    if (s > M) return;
    int lo = 0, hi = n;
    while (lo < hi) { int mid = (lo + hi) >> 1; if (pt_inv[mid] < s) lo = mid + 1; else hi = mid; }
    starts[s] = lo;
}

__global__ __launch_bounds__(256) void pool_gemm_kernel(
    const int* __restrict__ shuffled_ind, const float* __restrict__ g,
    const float* __restrict__ l, const int* __restrict__ starts,
    const float* __restrict__ W, const float* __restrict__ b,
    float* __restrict__ out, int M)
{
    __shared__ float Ws[D_IN * K_OUT];
    __shared__ float bs[K_OUT];
    __shared__ float pool[WPB][D_IN];
    const int tid = threadIdx.x;
    for (int i = tid; i < D_IN * K_OUT; i += 256) Ws[i] = W[i];
    if (tid < K_OUT) bs[tid] = b[tid];
    const int wid = tid >> 6, lane = tid & 63;
    const int s = blockIdx.x * WPB + wid;
    const bool active = (s < M);
    float m = -INFINITY;
    if (active) {
        const int p0 = starts[s], p1 = starts[s + 1];
        for (int p = p0; p < p1; ++p) {
            const int ind = shuffled_ind[p];
            m = fmaxf(m, g[(size_t)ind * D_IN + lane] + l[(size_t)p * D_IN + lane]);
        }
        if (p1 <= p0) m = 0.0f;
    }
    if (active) pool[wid][lane] = m;
    __syncthreads();
    if (active && lane < K_OUT) {
        float acc = bs[lane];
        #pragma unroll
        for (int c = 0; c < D_IN; ++c) acc = fmaf(pool[wid][c], Ws[c * K_OUT + lane], acc);
        out[(size_t)s * K_OUT + lane] = fmaxf(acc, 0.0f);
    }
}

extern "C" void kernel_launch(void* const* d_in, const int* in_sizes, int n_in,
                              void* d_out, int out_size, void* d_ws, size_t ws_size,
                              hipStream_t stream)
{
    const int*   shuffled_ind = (const int*)  d_in[0];
    const float* g            = (const float*)d_in[1];
    const float* l            = (const float*)d_in[2];
    const int*   pt_inv       = (const int*)  d_in[3];
    const float* W            = (const float*)d_in[4];
    const float* b            = (const float*)d_in[5];
    float*       out          = (float*)d_out;

    const int N = in_sizes[0];
    const int M = out_size / K_OUT;

    const size_t pooled_bytes = (size_t)M * D_IN * sizeof(unsigned);

    if (ws_size >= pooled_bytes && (N % 4) == 0 && N >= 8) {
        unsigned* pooled = (unsigned*)d_ws;
        {
            const int n4 = (int)(pooled_bytes / 16);
            init_pooled_kernel<<<512, 256, 0, stream>>>((uint4*)pooled, n4);
        }
        {
            const int waves  = (N + RPW - 1) / RPW;
            const int blocks = (waves + WPB - 1) / WPB;
            scan_strip_kernel<<<blocks, 64 * WPB, 0, stream>>>(
                shuffled_ind, g, l, pt_inv, pooled, N);
        }
        {
            const int blocks = (M + 2 * WPB - 1) / (2 * WPB);
            gemm_kernel<<<blocks, 64 * WPB, 0, stream>>>(pooled, W, b, out, M);
        }
    } else {
        int* starts = (int*)d_ws;
        {
            const int blocks = (M + 1 + 255) / 256;
            seg_starts_kernel<<<blocks, 256, 0, stream>>>(pt_inv, N, starts, M);
        }
        {
            const int blocks = (M + WPB - 1) / WPB;
            pool_gemm_kernel<<<blocks, 64 * WPB, 0, stream>>>(
                shuffled_ind, g, l, starts, W, b, out, M);
        }
    }
}